// Round 7
// baseline (345.025 us; speedup 1.0000x reference)
//
#include <hip/hip_runtime.h>
#include <hip/hip_bf16.h>

typedef __hip_bfloat16 bf16;
typedef __attribute__((ext_vector_type(8))) short short8;   // 8 bf16 (4 VGPRs)
typedef __attribute__((ext_vector_type(4))) short short4v;  // 4 bf16 (2 VGPRs)
typedef __attribute__((ext_vector_type(4))) float f32x4;
typedef unsigned int uint32;

#define MFMA16(a, b, c) __builtin_amdgcn_mfma_f32_16x16x32_bf16(a, b, c, 0, 0, 0)

// 16x16x16 bf16 MFMA (K=16): B-frag k-layout = quad*4+i, which exactly matches
// the C-layout rows (quad*4+r) of a prior 16x16 MFMA -> P can stay in regs.
__device__ __forceinline__ f32x4 MFMA16K16(short4v a, short4v b, f32x4 c) {
#if __has_builtin(__builtin_amdgcn_mfma_f32_16x16x16bf16_1k)
    return __builtin_amdgcn_mfma_f32_16x16x16bf16_1k(a, b, c, 0, 0, 0);
#else
    asm("v_mfma_f32_16x16x16_bf16 %0, %1, %2, %0" : "+v"(c) : "v"(a), "v"(b));
    return c;
#endif
}

constexpr int EMB   = 1024;
constexpr int SEQ   = 2048;
constexpr int BATCH = 4;
constexpr int NH    = 16;
constexpr int HD    = 64;
constexpr int QKVW  = 3 * EMB;   // 3072, stride of fused QKV buffer
// softmax scale 1/sqrt(64) folded into Q projection, in log2 units
constexpr float QSCALE = 0.125f * 1.44269504f;

// async global->LDS, 16B per lane; LDS dest = wave-uniform base + lane*16
__device__ __forceinline__ void gl_lds16(const bf16* g, bf16* l) {
    __builtin_amdgcn_global_load_lds(
        (const __attribute__((address_space(1))) void*)g,
        (__attribute__((address_space(3))) void*)l,
        16, 0, 0);
}

__device__ __forceinline__ float fexp2(float x) {
#if __has_builtin(__builtin_amdgcn_exp2f)
    return __builtin_amdgcn_exp2f(x);   // single v_exp_f32
#else
    return exp2f(x);
#endif
}

// pack two f32 -> bf16x2 (round-half-up): add 0x8000, take high halves via perm.
__device__ __forceinline__ uint32 pack2(float a, float b) {
    uint32 ua = __builtin_bit_cast(uint32, a) + 0x8000u;
    uint32 ub = __builtin_bit_cast(uint32, b) + 0x8000u;
    return __builtin_amdgcn_perm(ub, ua, 0x07060302u);  // {ub.hi16, ua.hi16}
}

__device__ __forceinline__ bf16 fbf16(float f) {        // fast scalar convert
    unsigned short u =
        (unsigned short)((__builtin_bit_cast(uint32, f) + 0x8000u) >> 16);
    return __builtin_bit_cast(bf16, u);
}

// ---------------------------------------------------------------------------
// One fused conversion kernel: x -> xc, {Wq,Wk,Wv} -> Wqkv (row-concat),
// Wo -> Woc. 3072 blocks: [0,2048) x, then 4x256 for the weights.
// ---------------------------------------------------------------------------
__global__ void convert_all(const float* __restrict__ x,
                            const float* __restrict__ wq,
                            const float* __restrict__ wk,
                            const float* __restrict__ wv,
                            const float* __restrict__ wo,
                            bf16* __restrict__ xc,
                            bf16* __restrict__ wqkv,
                            bf16* __restrict__ woc) {
    const int NX = BATCH * SEQ * EMB;
    const int NW = EMB * EMB;
    const float* src; bf16* dst; int n4, b0, nb;
    const int blk = blockIdx.x;
    if (blk < 2048)      { src = x;  dst = xc;          n4 = NX / 4; b0 = 0;    nb = 2048; }
    else if (blk < 2304) { src = wq; dst = wqkv;        n4 = NW / 4; b0 = 2048; nb = 256; }
    else if (blk < 2560) { src = wk; dst = wqkv + NW;   n4 = NW / 4; b0 = 2304; nb = 256; }
    else if (blk < 2816) { src = wv; dst = wqkv + 2*NW; n4 = NW / 4; b0 = 2560; nb = 256; }
    else                 { src = wo; dst = woc;         n4 = NW / 4; b0 = 2816; nb = 256; }
    for (int i = (blk - b0) * 256 + threadIdx.x; i < n4; i += nb * 256) {
        float4 v = ((const float4*)src)[i];
        uint2 o;
        o.x = pack2(v.x, v.y);
        o.y = pack2(v.z, v.w);
        ((uint2*)dst)[i] = o;
    }
}

// ---------------------------------------------------------------------------
// GEMM: C[M,N] = A[M,K]*B[N,K]^T (R4: dbuf + counted vmcnt, m-fastest XCD
// chunks -> per-XCD window = A 2MB + B 2MB = L2). Unchanged.
// ---------------------------------------------------------------------------
template <typename OutT>
__global__ __launch_bounds__(256) void gemm_bt(const bf16* __restrict__ A,
                                               const bf16* __restrict__ B,
                                               OutT* __restrict__ C,
                                               int M, int N, int K,
                                               float oscale, int qlim) {
    __shared__ __align__(16) bf16 As[2][128 * 64];
    __shared__ __align__(16) bf16 Bs[2][128 * 64];

    const int t    = threadIdx.x;
    const int lane = t & 63;
    const int wid  = t >> 6;
    const int l16  = lane & 15;
    const int quad = lane >> 4;
    const int e    = l16 & 7;            // swizzle key for reads
    const int wm   = (wid >> 1) * 64;
    const int wn   = (wid & 1) * 64;

    const int nwg   = (int)gridDim.x;
    const int cpx   = nwg >> 3;                     // blocks per XCD chunk
    const int gx    = N >> 7;                       // tiles along N
    const int mrows = cpx / gx;                     // M-tile rows per chunk
    const int xcd   = (int)blockIdx.x & 7;
    const int local = (int)blockIdx.x >> 3;         // 0..cpx-1
    const int m0    = (xcd * mrows + (local % mrows)) * 128;
    const int n0    = (local / mrows) * 128;
    const float sc  = (n0 < qlim) ? oscale : 1.0f;

    f32x4 acc[4][4] = {};
    const int srow = lane >> 3;                    // 0..7
    const int scol = ((lane & 7) ^ srow) * 8;      // swizzled staging column

    auto stage = [&](int kt, int buf) {
        const int k0 = kt * 64;
        #pragma unroll
        for (int it = 0; it < 4; ++it) {
            int rb = it * 32 + wid * 8;  // wave-uniform LDS row base
            gl_lds16(&A[(size_t)(m0 + rb + srow) * K + k0 + scol], &As[buf][rb * 64]);
            gl_lds16(&B[(size_t)(n0 + rb + srow) * K + k0 + scol], &Bs[buf][rb * 64]);
        }
    };

    const int nk = K >> 6;                         // 16 for K=1024
    stage(0, 0);
    stage(1, 1);

    for (int kt = 0; kt < nk; ++kt) {
        const int cur = kt & 1;
        if (kt < nk - 1) __builtin_amdgcn_s_waitcnt(0x0F78);   // vmcnt(8)
        else             __builtin_amdgcn_s_waitcnt(0x0F70);   // vmcnt(0)
        __builtin_amdgcn_s_barrier();

        #pragma unroll
        for (int ks = 0; ks < 64; ks += 32) {
            const int cb = (ks >> 3) + quad;       // col-block before swizzle
            short8 af[4], bfr[4];
            #pragma unroll
            for (int i = 0; i < 4; ++i)
                af[i] = *(const short8*)&As[cur][(wm + i * 16 + l16) * 64 + ((cb ^ e) * 8)];
            #pragma unroll
            for (int j = 0; j < 4; ++j)
                bfr[j] = *(const short8*)&Bs[cur][(wn + j * 16 + l16) * 64 + ((cb ^ e) * 8)];
            #pragma unroll
            for (int i = 0; i < 4; ++i)
                #pragma unroll
                for (int j = 0; j < 4; ++j)
                    acc[i][j] = MFMA16(af[i], bfr[j], acc[i][j]);
        }

        __builtin_amdgcn_s_barrier();              // all waves done with buf[cur]
        if (kt + 2 < nk) stage(kt + 2, cur);       // prefetch into freed buffer
    }

    // C/D layout: col(n)=l16, row(m)=quad*4+reg  [m89/m91]
    #pragma unroll
    for (int i = 0; i < 4; ++i)
        #pragma unroll
        for (int j = 0; j < 4; ++j)
            #pragma unroll
            for (int r = 0; r < 4; ++r) {
                int row = m0 + wm + i * 16 + quad * 4 + r;
                int col = n0 + wn + j * 16 + l16;
                float v = acc[i][j][r] * sc;
                if constexpr (sizeof(OutT) == 2)
                    C[(size_t)row * N + col] = fbf16(v);
                else
                    C[(size_t)row * N + col] = (OutT)v;
            }
}

// ---------------------------------------------------------------------------
// V transpose out of fused QKV: QKV[b*S+s][2048 + h*64 + d] -> Vt[bh][d][s]
// ---------------------------------------------------------------------------
__global__ __launch_bounds__(256) void transpose_v(const bf16* __restrict__ QKV,
                                                   bf16* __restrict__ Vt) {
    __shared__ __align__(16) bf16 Ts[4096];   // 64x64, 16B-block XOR swizzle
    const int t  = threadIdx.x;
    const int st = blockIdx.x;
    const int bh = blockIdx.y;
    const int b  = bh >> 4, h = bh & 15;
    const int s0 = st * 64;

    const bf16* src = QKV + ((size_t)(b * SEQ + s0)) * QKVW + 2 * EMB + h * HD;
    {
        int r = t >> 3, cq = t & 7;
        #pragma unroll
        for (int it = 0; it < 2; ++it, r += 32) {
            uint4 v = *(const uint4*)&src[(size_t)r * QKVW + cq * 8];
            int blk = cq ^ (r >> 3);
            *(uint4*)&Ts[r * 64 + blk * 8] = v;
        }
    }
    __syncthreads();
    bf16* dst = Vt + (size_t)bh * HD * SEQ + s0;
    {
        int d = t >> 3;
        const int sq = t & 7;
        #pragma unroll
        for (int it = 0; it < 2; ++it, d += 32) {
            short8 ov;
            #pragma unroll
            for (int i = 0; i < 8; ++i) {
                int s = sq * 8 + i;
                ov[i] = (short)__bfloat16_as_ushort(
                    Ts[s * 64 + (((d >> 3) ^ sq) << 3) + (d & 7)]);
            }
            *(short8*)&dst[(size_t)d * SEQ + sq * 8] = ov;
        }
    }
}

// ---------------------------------------------------------------------------
// Flash attention (causal), R6 = R5 k-loop + R3 occupancy.
//
// R5 lesson: key-split k-loop (in-reg P, 4.5x less LDS traffic) is good, but
// 67.5KB LDS -> 2 blocks/CU (8 waves) + 4 heavy epilogues = net regression.
// R6: 1024 blocks = 64 bh x 16 pairs {31-pr, pr} (2 passes, 33 uniform
// k-tile-units); epilogue reduced via 2-step XOR tree (8 slots [16][65] f32
// overlaying dead staging) -> LDS 34304 B -> 4 blocks/CU, 16 waves/CU.
// All o[] accesses use compile-time dg + wave-uniform guards (rule #20).
// Staging pipeline (dbuf, vmcnt(4), raw barriers) unchanged.
// XCD chunk = 128 blocks = 8 bh -> per-XCD K/V working set 4 MB = its L2.
// ---------------------------------------------------------------------------
__global__ __launch_bounds__(256, 4) void flash_attn(const bf16* __restrict__ QKV,
                                                     const bf16* __restrict__ Vt,
                                                     bf16* __restrict__ O) {
    // 8576 floats = 34304 B.
    //   k-loop:   Ks [2][64*64] bf16 = floats [0..4096)
    //             VTs[2][64*64] bf16 = floats [4096..8192)
    //   epilogue: 8 slots x [16][65] f32 at slot(w,i)=(w*2+i)*1040, [0..8320)
    //             lred [4 waves][64 q] at [8320..8576)
    __shared__ __align__(16) float smemF[8576];
    bf16* Ks  = (bf16*)smemF;                 // [2][64*64] keys x d, swizzled
    bf16* VTs = (bf16*)smemF + 8192;          // [2][64*64] d x keys, swizzled
    constexpr int LRED = 8320;

    const int t    = threadIdx.x;
    const int lane = t & 63;
    const int w    = t >> 6;
    const int l16  = lane & 15;
    const int quad = lane >> 4;
    const int e    = l16 & 7;
    const int w16k = w * 16;

    // XCD-chunk swizzle: 1024 blocks, chunk 128 = 8 bh x 16 pr
    const int lin = (int)blockIdx.x;
    const int wg  = ((lin & 7) << 7) + (lin >> 3);
    const int bh  = wg >> 4;                         // 0..63
    const int pr  = wg & 15;                         // 0..15
    const int b   = bh >> 4, h = bh & 15;

    const bf16* Qp = QKV + (size_t)b * SEQ * QKVW + h * HD;
    const bf16* Kp = QKV + (size_t)b * SEQ * QKVW + EMB + h * HD;
    const bf16* Vp = Vt + (size_t)bh * HD * SEQ;
    bf16* Op = O + (size_t)b * SEQ * EMB + h * HD;

    const int srow = lane >> 3;
    const int scol = ((lane & 7) ^ srow) * 8;   // swizzled staging column

    auto stage = [&](int kt, int buf) {
        const int kbase = kt * 64;
        #pragma unroll
        for (int it = 0; it < 2; ++it) {
            int rb = it * 32 + w * 8;
            gl_lds16(&Kp[(size_t)(kbase + rb + srow) * QKVW + scol], &Ks[buf * 4096 + rb * 64]);
            gl_lds16(&Vp[(size_t)(rb + srow) * SEQ + kbase + scol], &VTs[buf * 4096 + rb * 64]);
        }
    };

    for (int pass = 0; pass < 2; ++pass) {
        const int qt = pass ? pr : 31 - pr;          // heavy q-tile first
        const int q0 = qt * 64;

        // Q fragments (B-operand, all 64 queries): B[k=quad*8+i][n=l16]
        short8 bQ[4][2];
        #pragma unroll
        for (int qg = 0; qg < 4; ++qg) {
            const size_t qr = (size_t)(q0 + qg * 16 + l16) * QKVW;
            bQ[qg][0] = *(const short8*)&Qp[qr + quad * 8];
            bQ[qg][1] = *(const short8*)&Qp[qr + 32 + quad * 8];
        }

        f32x4 o[4][4] = {};          // partial O^T[dg][qg], this wave's 16 keys
        float lrow[4] = {0.f, 0.f, 0.f, 0.f};

        const int ntiles = qt + 1;

        stage(0, 0);
        if (ntiles > 1) stage(1, 1);

        for (int kt = 0; kt < ntiles; ++kt) {
            const int cur = kt & 1;
            const int kbase = kt * 64;
            if (kt < ntiles - 1) __builtin_amdgcn_s_waitcnt(0x0F74);   // vmcnt(4)
            else                 __builtin_amdgcn_s_waitcnt(0x0F70);   // vmcnt(0)
            __builtin_amdgcn_s_barrier();

            // --- K fragments: this wave's 16 keys, d=0..63 (A-operand) ---
            const bf16* Kb = &Ks[cur * 4096];
            const short8 kf0 = *(const short8*)&Kb[(w16k + l16) * 64 + ((quad ^ e) * 8)];
            const short8 kf1 = *(const short8*)&Kb[(w16k + l16) * 64 + (((4 + quad) ^ e) * 8)];

            // --- S^T = K Q^T per q-group; exp; pack to in-reg P fragments ---
            short4v pb[4];
            const bool diag = (kt == ntiles - 1);
            const int kgb = kbase + w16k + quad * 4;
            #pragma unroll
            for (int qg = 0; qg < 4; ++qg) {
                f32x4 acc = {};
                acc = MFMA16(kf0, bQ[qg][0], acc);
                acc = MFMA16(kf1, bQ[qg][1], acc);
                // col=query=l16 (+16*qg), row=key=quad*4+r (+w16k)
                float p0 = fexp2(acc[0]);
                float p1 = fexp2(acc[1]);
                float p2 = fexp2(acc[2]);
                float p3 = fexp2(acc[3]);
                if (diag) {
                    const int qglob = q0 + qg * 16 + l16;
                    if (kgb     > qglob) p0 = 0.f;
                    if (kgb + 1 > qglob) p1 = 0.f;
                    if (kgb + 2 > qglob) p2 = 0.f;
                    if (kgb + 3 > qglob) p3 = 0.f;
                }
                lrow[qg] += (p0 + p1) + (p2 + p3);
                uint2 u;
                u.x = pack2(p0, p1);
                u.y = pack2(p2, p3);
                pb[qg] = __builtin_bit_cast(short4v, u);
            }

            // --- O^T += V^T P^T : A=V^T[16 d][16 keys] (b64), B=pb (in-reg) ---
            const bf16* Vb = &VTs[cur * 4096];
            #pragma unroll
            for (int dg = 0; dg < 4; ++dg) {
                const short4v vf = *(const short4v*)&Vb[(dg * 16 + l16) * 64 +
                    (((2 * w + (quad >> 1)) ^ e) * 8) + (quad & 1) * 4];
                #pragma unroll
                for (int qg = 0; qg < 4; ++qg)
                    o[dg][qg] = MFMA16K16(vf, pb[qg], o[dg][qg]);
            }

            __builtin_amdgcn_s_barrier();
            if (kt + 2 < ntiles) stage(kt + 2, cur);
        }

        // ---- epilogue: 2-step XOR tree-reduce of O^T across waves ----
        #pragma unroll
        for (int qg = 0; qg < 4; ++qg) {            // reduce l over quads
            float l = lrow[qg];
            l += __shfl_xor(l, 16);
            l += __shfl_xor(l, 32);
            lrow[qg] = l;
        }
        if (quad == 0) {
            #pragma unroll
            for (int qg = 0; qg < 4; ++qg)
                smemF[LRED + w * 64 + qg * 16 + l16] = lrow[qg];
        }
        // step 1 write: d == w^1 -> slot(w,0), d == w^3 -> slot(w,1)
        {
            float* s1a = smemF + (w * 2 + 0) * 1040;
            float* s1b = smemF + (w * 2 + 1) * 1040;
            #pragma unroll
            for (int dg = 0; dg < 4; ++dg) {
                if (dg == (w ^ 1)) {
                    #pragma unroll
                    for (int r = 0; r < 4; ++r)
                        #pragma unroll
                        for (int qg = 0; qg < 4; ++qg)
                            s1a[(quad * 4 + r) * 65 + qg * 16 + l16] = o[dg][qg][r];
                }
                if (dg == (w ^ 3)) {
                    #pragma unroll
                    for (int r = 0; r < 4; ++r)
                        #pragma unroll
                        for (int qg = 0; qg < 4; ++qg)
                            s1b[(quad * 4 + r) * 65 + qg * 16 + l16] = o[dg][qg][r];
                }
            }
        }
        __syncthreads();
        // step 1 read: slot(w^1,0) holds d==w; slot(w^1,1) holds d==w^2
        {
            const float* r1a = smemF + ((w ^ 1) * 2 + 0) * 1040;
            const float* r1b = smemF + ((w ^ 1) * 2 + 1) * 1040;
            #pragma unroll
            for (int dg = 0; dg < 4; ++dg) {
                if (dg == w) {
                    #pragma unroll
                    for (int r = 0; r < 4; ++r)
                        #pragma unroll
                        for (int qg = 0; qg < 4; ++qg)
                            o[dg][qg][r] += r1a[(quad * 4 + r) * 65 + qg * 16 + l16];
                }
                if (dg == (w ^ 2)) {
                    #pragma unroll
                    for (int r = 0; r < 4; ++r)
                        #pragma unroll
                        for (int qg = 0; qg < 4; ++qg)
                            o[dg][qg][r] += r1b[(quad * 4 + r) * 65 + qg * 16 + l16];
                }
            }
        }
        __syncthreads();
        // step 2 write: d == w^2 (pair-summed) -> slot(w,0)
        {
            float* s2 = smemF + (w * 2 + 0) * 1040;
            #pragma unroll
            for (int dg = 0; dg < 4; ++dg) {
                if (dg == (w ^ 2)) {
                    #pragma unroll
                    for (int r = 0; r < 4; ++r)
                        #pragma unroll
                        for (int qg = 0; qg < 4; ++qg)
                            s2[(quad * 4 + r) * 65 + qg * 16 + l16] = o[dg][qg][r];
                }
            }
        }
        __syncthreads();
        // step 2 read + finalize: slot(w^2,0) holds d==w over the other pair
        {
            const float* r2 = smemF + ((w ^ 2) * 2 + 0) * 1040;
            float rlq[4];
            #pragma unroll
            for (int qg = 0; qg < 4; ++qg) {
                float s0 = smemF[LRED +       qg * 16 + l16]
                         + smemF[LRED +  64 + qg * 16 + l16]
                         + smemF[LRED + 128 + qg * 16 + l16]
                         + smemF[LRED + 192 + qg * 16 + l16];
                rlq[qg] = 1.0f / s0;
            }
            float* Of = smemF + (w * 2 + 1) * 1040;   // free after step-1 read
            #pragma unroll
            for (int dg = 0; dg < 4; ++dg) {
                if (dg == w) {
                    #pragma unroll
                    for (int r = 0; r < 4; ++r)
                        #pragma unroll
                        for (int qg = 0; qg < 4; ++qg)
                            Of[(quad * 4 + r) * 65 + qg * 16 + l16] =
                                (o[dg][qg][r] +
                                 r2[(quad * 4 + r) * 65 + qg * 16 + l16]) * rlq[qg];
                }
            }
            // wave-private transposed readback (lgkm-ordered), coalesced store
            float f[16];
            #pragma unroll
            for (int d = 0; d < 16; ++d) f[d] = Of[d * 65 + lane];
            uint4 ua, ub;
            ua.x = pack2(f[0],  f[1]);  ua.y = pack2(f[2],  f[3]);
            ua.z = pack2(f[4],  f[5]);  ua.w = pack2(f[6],  f[7]);
            ub.x = pack2(f[8],  f[9]);  ub.y = pack2(f[10], f[11]);
            ub.z = pack2(f[12], f[13]); ub.w = pack2(f[14], f[15]);
            *(uint4*)&Op[(size_t)(q0 + lane) * EMB + w16k]     = ua;
            *(uint4*)&Op[(size_t)(q0 + lane) * EMB + w16k + 8] = ub;
        }
        __syncthreads();   // scratch free before next pass's stage() overwrites
    }
}

// ---------------------------------------------------------------------------
extern "C" void kernel_launch(void* const* d_in, const int* in_sizes, int n_in,
                              void* d_out, int out_size, void* d_ws, size_t ws_size,
                              hipStream_t stream) {
    const float* x  = (const float*)d_in[0];
    const float* Wq = (const float*)d_in[1];
    const float* Wk = (const float*)d_in[2];
    const float* Wv = (const float*)d_in[3];
    const float* Wo = (const float*)d_in[4];
    float* out = (float*)d_out;            // reference output dtype: float32
    bf16*  ws  = (bf16*)d_ws;

    const int M  = BATCH * SEQ;            // 8192
    const int NX = M * EMB;                // 8388608
    const int NW = EMB * EMB;              // 1048576

    // workspace (bf16 elems), total 92,274,688 B
    bf16* xc   = ws;                       // [8192][1024]; dead after QKV GEMM
    bf16* Ab   = xc;                       // attention out aliases xc
    bf16* Wqkv = ws + (size_t)NX;          // [3072][1024] fused weights
    bf16* Woc  = Wqkv + 3 * (size_t)NW;
    bf16* QKV  = Woc + NW;                 // [8192][3072]
    bf16* Vt   = QKV + (size_t)M * QKVW;   // [64 bh][64 d][2048 s]

    // 1) one fused conversion launch
    convert_all<<<3072, 256, 0, stream>>>(x, Wq, Wk, Wv, Wo, xc, Wqkv, Woc);

    // 2) fused QKV projection (Q cols pre-scaled by QSCALE), XCD-swizzled 1D grid
    gemm_bt<bf16><<<dim3((QKVW / 128) * (M / 128)), 256, 0, stream>>>(
        xc, Wqkv, QKV, M, QKVW, EMB, QSCALE, EMB);

    // 3) V transpose into [bh][d][s]
    transpose_v<<<dim3(SEQ / 64, BATCH * NH), 256, 0, stream>>>(QKV, Vt);

    // 4) causal flash attention: 1024 uniform blocks (paired 64-row q-tiles,
    //    key-split waves, in-reg P, tree-reduce epilogue), 4 blocks/CU
    flash_attn<<<dim3(1024), 256, 0, stream>>>(QKV, Vt, Ab);

    // 5) output projection -> fp32, XCD-swizzled 1D grid
    gemm_bt<float><<<dim3((EMB / 128) * (M / 128)), 256, 0, stream>>>(
        Ab, Woc, out, M, EMB, EMB, 1.0f, 0);
}

// Round 8
// 237.840 us; speedup vs baseline: 1.4507x; 1.4507x over previous
//
#include <hip/hip_runtime.h>
#include <hip/hip_bf16.h>

typedef __hip_bfloat16 bf16;
typedef __attribute__((ext_vector_type(8))) short short8;   // 8 bf16 (4 VGPRs)
typedef __attribute__((ext_vector_type(4))) short short4v;  // 4 bf16 (2 VGPRs)
typedef __attribute__((ext_vector_type(4))) float f32x4;
typedef unsigned int uint32;

#define MFMA16(a, b, c) __builtin_amdgcn_mfma_f32_16x16x32_bf16(a, b, c, 0, 0, 0)

// 16x16x16 bf16 MFMA (K=16): B-frag k-layout = quad*4+i, which exactly matches
// the C-layout rows (quad*4+r) of a prior 16x16 MFMA -> P can stay in regs.
__device__ __forceinline__ f32x4 MFMA16K16(short4v a, short4v b, f32x4 c) {
#if __has_builtin(__builtin_amdgcn_mfma_f32_16x16x16bf16_1k)
    return __builtin_amdgcn_mfma_f32_16x16x16bf16_1k(a, b, c, 0, 0, 0);
#else
    asm("v_mfma_f32_16x16x16_bf16 %0, %1, %2, %0" : "+v"(c) : "v"(a), "v"(b));
    return c;
#endif
}

constexpr int EMB   = 1024;
constexpr int SEQ   = 2048;
constexpr int BATCH = 4;
constexpr int NH    = 16;
constexpr int HD    = 64;
constexpr int QKVW  = 3 * EMB;   // 3072, stride of fused QKV buffer
// softmax scale 1/sqrt(64) folded into Q projection, in log2 units
constexpr float QSCALE = 0.125f * 1.44269504f;

// async global->LDS, 16B per lane; LDS dest = wave-uniform base + lane*16
__device__ __forceinline__ void gl_lds16(const bf16* g, bf16* l) {
    __builtin_amdgcn_global_load_lds(
        (const __attribute__((address_space(1))) void*)g,
        (__attribute__((address_space(3))) void*)l,
        16, 0, 0);
}

__device__ __forceinline__ float fexp2(float x) {
#if __has_builtin(__builtin_amdgcn_exp2f)
    return __builtin_amdgcn_exp2f(x);   // single v_exp_f32
#else
    return exp2f(x);
#endif
}

// pack two f32 -> bf16x2 (round-half-up): add 0x8000, take high halves via perm.
__device__ __forceinline__ uint32 pack2(float a, float b) {
    uint32 ua = __builtin_bit_cast(uint32, a) + 0x8000u;
    uint32 ub = __builtin_bit_cast(uint32, b) + 0x8000u;
    return __builtin_amdgcn_perm(ub, ua, 0x07060302u);  // {ub.hi16, ua.hi16}
}

__device__ __forceinline__ bf16 fbf16(float f) {        // fast scalar convert
    unsigned short u =
        (unsigned short)((__builtin_bit_cast(uint32, f) + 0x8000u) >> 16);
    return __builtin_bit_cast(bf16, u);
}

// ---------------------------------------------------------------------------
// One fused conversion kernel: x -> xc, {Wq,Wk,Wv} -> Wqkv (row-concat),
// Wo -> Woc. 3072 blocks: [0,2048) x, then 4x256 for the weights.
// ---------------------------------------------------------------------------
__global__ void convert_all(const float* __restrict__ x,
                            const float* __restrict__ wq,
                            const float* __restrict__ wk,
                            const float* __restrict__ wv,
                            const float* __restrict__ wo,
                            bf16* __restrict__ xc,
                            bf16* __restrict__ wqkv,
                            bf16* __restrict__ woc) {
    const int NX = BATCH * SEQ * EMB;
    const int NW = EMB * EMB;
    const float* src; bf16* dst; int n4, b0, nb;
    const int blk = blockIdx.x;
    if (blk < 2048)      { src = x;  dst = xc;          n4 = NX / 4; b0 = 0;    nb = 2048; }
    else if (blk < 2304) { src = wq; dst = wqkv;        n4 = NW / 4; b0 = 2048; nb = 256; }
    else if (blk < 2560) { src = wk; dst = wqkv + NW;   n4 = NW / 4; b0 = 2304; nb = 256; }
    else if (blk < 2816) { src = wv; dst = wqkv + 2*NW; n4 = NW / 4; b0 = 2560; nb = 256; }
    else                 { src = wo; dst = woc;         n4 = NW / 4; b0 = 2816; nb = 256; }
    for (int i = (blk - b0) * 256 + threadIdx.x; i < n4; i += nb * 256) {
        float4 v = ((const float4*)src)[i];
        uint2 o;
        o.x = pack2(v.x, v.y);
        o.y = pack2(v.z, v.w);
        ((uint2*)dst)[i] = o;
    }
}

// ---------------------------------------------------------------------------
// GEMM: C[M,N] = A[M,K]*B[N,K]^T (R4: dbuf + counted vmcnt, m-fastest XCD
// chunks -> per-XCD window = A 2MB + B 2MB = L2). Unchanged.
// ---------------------------------------------------------------------------
template <typename OutT>
__global__ __launch_bounds__(256) void gemm_bt(const bf16* __restrict__ A,
                                               const bf16* __restrict__ B,
                                               OutT* __restrict__ C,
                                               int M, int N, int K,
                                               float oscale, int qlim) {
    __shared__ __align__(16) bf16 As[2][128 * 64];
    __shared__ __align__(16) bf16 Bs[2][128 * 64];

    const int t    = threadIdx.x;
    const int lane = t & 63;
    const int wid  = t >> 6;
    const int l16  = lane & 15;
    const int quad = lane >> 4;
    const int e    = l16 & 7;            // swizzle key for reads
    const int wm   = (wid >> 1) * 64;
    const int wn   = (wid & 1) * 64;

    const int nwg   = (int)gridDim.x;
    const int cpx   = nwg >> 3;                     // blocks per XCD chunk
    const int gx    = N >> 7;                       // tiles along N
    const int mrows = cpx / gx;                     // M-tile rows per chunk
    const int xcd   = (int)blockIdx.x & 7;
    const int local = (int)blockIdx.x >> 3;         // 0..cpx-1
    const int m0    = (xcd * mrows + (local % mrows)) * 128;
    const int n0    = (local / mrows) * 128;
    const float sc  = (n0 < qlim) ? oscale : 1.0f;

    f32x4 acc[4][4] = {};
    const int srow = lane >> 3;                    // 0..7
    const int scol = ((lane & 7) ^ srow) * 8;      // swizzled staging column

    auto stage = [&](int kt, int buf) {
        const int k0 = kt * 64;
        #pragma unroll
        for (int it = 0; it < 4; ++it) {
            int rb = it * 32 + wid * 8;  // wave-uniform LDS row base
            gl_lds16(&A[(size_t)(m0 + rb + srow) * K + k0 + scol], &As[buf][rb * 64]);
            gl_lds16(&B[(size_t)(n0 + rb + srow) * K + k0 + scol], &Bs[buf][rb * 64]);
        }
    };

    const int nk = K >> 6;                         // 16 for K=1024
    stage(0, 0);
    stage(1, 1);

    for (int kt = 0; kt < nk; ++kt) {
        const int cur = kt & 1;
        if (kt < nk - 1) __builtin_amdgcn_s_waitcnt(0x0F78);   // vmcnt(8)
        else             __builtin_amdgcn_s_waitcnt(0x0F70);   // vmcnt(0)
        __builtin_amdgcn_s_barrier();

        #pragma unroll
        for (int ks = 0; ks < 64; ks += 32) {
            const int cb = (ks >> 3) + quad;       // col-block before swizzle
            short8 af[4], bfr[4];
            #pragma unroll
            for (int i = 0; i < 4; ++i)
                af[i] = *(const short8*)&As[cur][(wm + i * 16 + l16) * 64 + ((cb ^ e) * 8)];
            #pragma unroll
            for (int j = 0; j < 4; ++j)
                bfr[j] = *(const short8*)&Bs[cur][(wn + j * 16 + l16) * 64 + ((cb ^ e) * 8)];
            #pragma unroll
            for (int i = 0; i < 4; ++i)
                #pragma unroll
                for (int j = 0; j < 4; ++j)
                    acc[i][j] = MFMA16(af[i], bfr[j], acc[i][j]);
        }

        __builtin_amdgcn_s_barrier();              // all waves done with buf[cur]
        if (kt + 2 < nk) stage(kt + 2, cur);       // prefetch into freed buffer
    }

    // C/D layout: col(n)=l16, row(m)=quad*4+reg  [m89/m91]
    #pragma unroll
    for (int i = 0; i < 4; ++i)
        #pragma unroll
        for (int j = 0; j < 4; ++j)
            #pragma unroll
            for (int r = 0; r < 4; ++r) {
                int row = m0 + wm + i * 16 + quad * 4 + r;
                int col = n0 + wn + j * 16 + l16;
                float v = acc[i][j][r] * sc;
                if constexpr (sizeof(OutT) == 2)
                    C[(size_t)row * N + col] = fbf16(v);
                else
                    C[(size_t)row * N + col] = (OutT)v;
            }
}

// ---------------------------------------------------------------------------
// V transpose out of fused QKV: QKV[b*S+s][2048 + h*64 + d] -> Vt[bh][d][s]
// ---------------------------------------------------------------------------
__global__ __launch_bounds__(256) void transpose_v(const bf16* __restrict__ QKV,
                                                   bf16* __restrict__ Vt) {
    __shared__ __align__(16) bf16 Ts[4096];   // 64x64, 16B-block XOR swizzle
    const int t  = threadIdx.x;
    const int st = blockIdx.x;
    const int bh = blockIdx.y;
    const int b  = bh >> 4, h = bh & 15;
    const int s0 = st * 64;

    const bf16* src = QKV + ((size_t)(b * SEQ + s0)) * QKVW + 2 * EMB + h * HD;
    {
        int r = t >> 3, cq = t & 7;
        #pragma unroll
        for (int it = 0; it < 2; ++it, r += 32) {
            uint4 v = *(const uint4*)&src[(size_t)r * QKVW + cq * 8];
            int blk = cq ^ (r >> 3);
            *(uint4*)&Ts[r * 64 + blk * 8] = v;
        }
    }
    __syncthreads();
    bf16* dst = Vt + (size_t)bh * HD * SEQ + s0;
    {
        int d = t >> 3;
        const int sq = t & 7;
        #pragma unroll
        for (int it = 0; it < 2; ++it, d += 32) {
            short8 ov;
            #pragma unroll
            for (int i = 0; i < 8; ++i) {
                int s = sq * 8 + i;
                ov[i] = (short)__bfloat16_as_ushort(
                    Ts[s * 64 + (((d >> 3) ^ sq) << 3) + (d & 7)]);
            }
            *(short8*)&dst[(size_t)d * SEQ + sq * 8] = ov;
        }
    }
}

// ---------------------------------------------------------------------------
// Flash attention (causal), R7: 2x2 hybrid split (keys x queries) + in-reg P.
//
// R6 post-mortem: 4-way key-split needs ~145 VGPR; __launch_bounds__(256,4)
// capped at 128 -> accumulator spills every k-tile -> 142 MB scratch writes,
// HBM-bound, 175us. R7 shrinks per-wave state to ~100 VGPR so the 128 cap is
// genuinely affordable: wave w = (kh=w>>1, qh=w&1) owns 32 keys x 32 queries,
// all 64 d. Same per-wave-tile arithmetic as R5/R6 (8 QK MFMA, 16 PV K16
// MFMA, 16 exp); LDS read redundancy 2x (vs R3 4x / R5 1x); P in registers
// (S^T rows quad*4+r == K16 B-frag k-layout). Epilogue: single partner
// exchange (w <-> w^2) + l-reduce, 2x/block. Diagonal tile: wave (kh=1,qh=0)
// fully masked -> skipped; mask only where kh==qh.
//
// Grid: 1024 uniform blocks = 64 bh x 16 pairs {31-pr, pr} (33 k-tile-units).
// LDS 33792 B -> 4 blocks/CU, 16 waves/CU. Staging pipeline (dbuf, vmcnt(4),
// raw barriers) identical to the R1-R6-verified one.
// XCD chunk = 128 blocks = 8 bh -> per-XCD K/V working set 4 MB = its L2.
// ---------------------------------------------------------------------------
__global__ __launch_bounds__(256, 4) void flash_attn(const bf16* __restrict__ QKV,
                                                     const bf16* __restrict__ Vt,
                                                     bf16* __restrict__ O) {
    // 8448 floats = 33792 B.
    //   k-loop:   Ks [2][64*64] bf16 = floats [0..4096)
    //             VTs[2][64*64] bf16 = floats [4096..8192)
    //   epilogue (overlaying dead staging, separated by syncthreads):
    //             slots: 8 x [16][33] f32, slot(qh,dg)=(qh*4+dg)*528, [0..4224)
    //             Of   : 4 x [32][33] f32, Of(w)=w*1056, [0..4224)
    //             lred : [4 waves][64 q] f32 at [8192..8448)
    __shared__ __align__(16) float smemF[8448];
    bf16* Ks  = (bf16*)smemF;                 // [2][64*64] keys x d, swizzled
    bf16* VTs = (bf16*)smemF + 8192;          // [2][64*64] d x keys, swizzled
    constexpr int LRED = 8192;

    const int t    = threadIdx.x;
    const int lane = t & 63;
    const int w    = t >> 6;
    const int l16  = lane & 15;
    const int quad = lane >> 4;
    const int e    = l16 & 7;
    const int kh   = w >> 1;                         // key half 0/1
    const int qh   = w & 1;                          // query half 0/1

    // XCD-chunk swizzle: 1024 blocks, chunk 128 = 8 bh x 16 pr
    const int lin = (int)blockIdx.x;
    const int wg  = ((lin & 7) << 7) + (lin >> 3);
    const int bh  = wg >> 4;                         // 0..63
    const int pr  = wg & 15;                         // 0..15
    const int b   = bh >> 4, h = bh & 15;

    const bf16* Qp = QKV + (size_t)b * SEQ * QKVW + h * HD;
    const bf16* Kp = QKV + (size_t)b * SEQ * QKVW + EMB + h * HD;
    const bf16* Vp = Vt + (size_t)bh * HD * SEQ;
    bf16* Op = O + (size_t)b * SEQ * EMB + h * HD;

    const int srow = lane >> 3;
    const int scol = ((lane & 7) ^ srow) * 8;   // swizzled staging column

    auto stage = [&](int kt, int buf) {
        const int kbase = kt * 64;
        #pragma unroll
        for (int it = 0; it < 2; ++it) {
            int rb = it * 32 + w * 8;
            gl_lds16(&Kp[(size_t)(kbase + rb + srow) * QKVW + scol], &Ks[buf * 4096 + rb * 64]);
            gl_lds16(&Vp[(size_t)(rb + srow) * SEQ + kbase + scol], &VTs[buf * 4096 + rb * 64]);
        }
    };

    for (int pass = 0; pass < 2; ++pass) {
        const int qt = pass ? pr : 31 - pr;          // heavy q-tile first
        const int q0 = qt * 64;

        // Q fragments (B-operand, this wave's 32 queries): B[k=quad*8+i][n=l16]
        short8 bQ[2][2];
        #pragma unroll
        for (int qg = 0; qg < 2; ++qg) {
            const size_t qr = (size_t)(q0 + qh * 32 + qg * 16 + l16) * QKVW;
            bQ[qg][0] = *(const short8*)&Qp[qr + quad * 8];
            bQ[qg][1] = *(const short8*)&Qp[qr + 32 + quad * 8];
        }

        f32x4 o[4][2] = {};          // partial O^T[dg][qg] over wave's 32 keys
        float lrow[2] = {0.f, 0.f};

        const int ntiles = qt + 1;

        stage(0, 0);
        if (ntiles > 1) stage(1, 1);

        for (int kt = 0; kt < ntiles; ++kt) {
            const int cur = kt & 1;
            const int kbase = kt * 64;
            if (kt < ntiles - 1) __builtin_amdgcn_s_waitcnt(0x0F74);   // vmcnt(4)
            else                 __builtin_amdgcn_s_waitcnt(0x0F70);   // vmcnt(0)
            __builtin_amdgcn_s_barrier();

            const bool diag = (kt == ntiles - 1);
            if (!(diag && kh == 1 && qh == 0)) {     // skip fully-masked wave
                // --- K fragments: wave's 32 keys (2 groups), d 0..63 ---
                const bf16* Kb = &Ks[cur * 4096];
                short8 kf[2][2];
                #pragma unroll
                for (int kg = 0; kg < 2; ++kg) {
                    const int krow = (kh * 32 + kg * 16 + l16) * 64;
                    kf[kg][0] = *(const short8*)&Kb[krow + ((quad ^ e) * 8)];
                    kf[kg][1] = *(const short8*)&Kb[krow + (((4 + quad) ^ e) * 8)];
                }

                // --- S^T = K Q^T; exp; pack to in-reg P fragments ---
                short4v pb[2][2];
                const bool needmask = diag && (kh == qh);
                #pragma unroll
                for (int kg = 0; kg < 2; ++kg) {
                    const int kgb = kbase + kh * 32 + kg * 16 + quad * 4;
                    #pragma unroll
                    for (int qg = 0; qg < 2; ++qg) {
                        f32x4 acc = {};
                        acc = MFMA16(kf[kg][0], bQ[qg][0], acc);
                        acc = MFMA16(kf[kg][1], bQ[qg][1], acc);
                        // col=q=l16 (+qh*32+qg*16), row=key=quad*4+r
                        float p0 = fexp2(acc[0]);
                        float p1 = fexp2(acc[1]);
                        float p2 = fexp2(acc[2]);
                        float p3 = fexp2(acc[3]);
                        if (needmask) {
                            const int qglob = q0 + qh * 32 + qg * 16 + l16;
                            if (kgb     > qglob) p0 = 0.f;
                            if (kgb + 1 > qglob) p1 = 0.f;
                            if (kgb + 2 > qglob) p2 = 0.f;
                            if (kgb + 3 > qglob) p3 = 0.f;
                        }
                        lrow[qg] += (p0 + p1) + (p2 + p3);
                        uint2 u;
                        u.x = pack2(p0, p1);
                        u.y = pack2(p2, p3);
                        pb[kg][qg] = __builtin_bit_cast(short4v, u);
                    }
                }

                // --- O^T += V^T P^T : A=V^T[16d][16k] b64, B=pb in regs ---
                const bf16* Vb = &VTs[cur * 4096];
                #pragma unroll
                for (int dg = 0; dg < 4; ++dg) {
                    #pragma unroll
                    for (int kg = 0; kg < 2; ++kg) {
                        const short4v vf = *(const short4v*)&Vb[(dg * 16 + l16) * 64 +
                            (((4 * kh + 2 * kg + (quad >> 1)) ^ e) * 8) + (quad & 1) * 4];
                        #pragma unroll
                        for (int qg = 0; qg < 2; ++qg)
                            o[dg][qg] = MFMA16K16(vf, pb[kg][qg], o[dg][qg]);
                    }
                }
            }

            __builtin_amdgcn_s_barrier();
            if (kt + 2 < ntiles) stage(kt + 2, cur);
        }

        // ---- epilogue: partner exchange (w <-> w^2), rescale, store ----
        #pragma unroll
        for (int qg = 0; qg < 2; ++qg) {            // reduce l over quads
            float l = lrow[qg];
            l += __shfl_xor(l, 16);
            l += __shfl_xor(l, 32);
            lrow[qg] = l;
        }
        if (quad == 0) {
            #pragma unroll
            for (int qg = 0; qg < 2; ++qg)
                smemF[LRED + w * 64 + qg * 16 + l16] = lrow[qg];
        }
        // step A: write partials for the d-half the partner finalizes
        #pragma unroll
        for (int dg = 0; dg < 4; ++dg) {
            if ((dg >> 1) != kh) {
                float* s = smemF + (qh * 4 + dg) * 528;
                #pragma unroll
                for (int r = 0; r < 4; ++r)
                    #pragma unroll
                    for (int qg = 0; qg < 2; ++qg)
                        s[(quad * 4 + r) * 33 + qg * 16 + l16] = o[dg][qg][r];
            }
        }
        __syncthreads();
        // step B: add partner partials for own finalized d-half; compute 1/l
        float rlq[2];
        {
            #pragma unroll
            for (int dg = 0; dg < 4; ++dg) {
                if ((dg >> 1) == kh) {
                    const float* s = smemF + (qh * 4 + dg) * 528;
                    #pragma unroll
                    for (int r = 0; r < 4; ++r)
                        #pragma unroll
                        for (int qg = 0; qg < 2; ++qg)
                            o[dg][qg][r] += s[(quad * 4 + r) * 33 + qg * 16 + l16];
                }
            }
            #pragma unroll
            for (int qg = 0; qg < 2; ++qg)
                rlq[qg] = 1.0f / (lrow[qg] +
                                  smemF[LRED + (w ^ 2) * 64 + qg * 16 + l16]);
        }
        __syncthreads();   // slots free before Of overwrite (same region)
        // step C: write finalized 32d x 32q to wave-private Of for transpose
        {
            float* Of = smemF + w * 1056;           // [32 d][33 q]
            #pragma unroll
            for (int dg = 0; dg < 4; ++dg) {
                if ((dg >> 1) == kh) {
                    const int dl = (dg & 1) * 16;
                    #pragma unroll
                    for (int r = 0; r < 4; ++r)
                        #pragma unroll
                        for (int qg = 0; qg < 2; ++qg)
                            Of[(dl + quad * 4 + r) * 33 + qg * 16 + l16] =
                                o[dg][qg][r] * rlq[qg];
                }
            }
            // step D: transposed readback (wave-private, lgkm-ordered), store
            const int qloc = lane >> 1, half = lane & 1;
            float f[16];
            #pragma unroll
            for (int j = 0; j < 16; ++j) f[j] = Of[(half * 16 + j) * 33 + qloc];
            uint4 ua, ub;
            ua.x = pack2(f[0],  f[1]);  ua.y = pack2(f[2],  f[3]);
            ua.z = pack2(f[4],  f[5]);  ua.w = pack2(f[6],  f[7]);
            ub.x = pack2(f[8],  f[9]);  ub.y = pack2(f[10], f[11]);
            ub.z = pack2(f[12], f[13]); ub.w = pack2(f[14], f[15]);
            bf16* orow = Op + (size_t)(q0 + qh * 32 + qloc) * EMB + kh * 32 + half * 16;
            *(uint4*)&orow[0] = ua;
            *(uint4*)&orow[8] = ub;
        }
        __syncthreads();   // scratch free before next pass's stage() overwrites
    }
}

// ---------------------------------------------------------------------------
extern "C" void kernel_launch(void* const* d_in, const int* in_sizes, int n_in,
                              void* d_out, int out_size, void* d_ws, size_t ws_size,
                              hipStream_t stream) {
    const float* x  = (const float*)d_in[0];
    const float* Wq = (const float*)d_in[1];
    const float* Wk = (const float*)d_in[2];
    const float* Wv = (const float*)d_in[3];
    const float* Wo = (const float*)d_in[4];
    float* out = (float*)d_out;            // reference output dtype: float32
    bf16*  ws  = (bf16*)d_ws;

    const int M  = BATCH * SEQ;            // 8192
    const int NX = M * EMB;                // 8388608
    const int NW = EMB * EMB;              // 1048576

    // workspace (bf16 elems), total 92,274,688 B
    bf16* xc   = ws;                       // [8192][1024]; dead after QKV GEMM
    bf16* Ab   = xc;                       // attention out aliases xc
    bf16* Wqkv = ws + (size_t)NX;          // [3072][1024] fused weights
    bf16* Woc  = Wqkv + 3 * (size_t)NW;
    bf16* QKV  = Woc + NW;                 // [8192][3072]
    bf16* Vt   = QKV + (size_t)M * QKVW;   // [64 bh][64 d][2048 s]

    // 1) one fused conversion launch
    convert_all<<<3072, 256, 0, stream>>>(x, Wq, Wk, Wv, Wo, xc, Wqkv, Woc);

    // 2) fused QKV projection (Q cols pre-scaled by QSCALE), XCD-swizzled 1D grid
    gemm_bt<bf16><<<dim3((QKVW / 128) * (M / 128)), 256, 0, stream>>>(
        xc, Wqkv, QKV, M, QKVW, EMB, QSCALE, EMB);

    // 3) V transpose into [bh][d][s]
    transpose_v<<<dim3(SEQ / 64, BATCH * NH), 256, 0, stream>>>(QKV, Vt);

    // 4) causal flash attention: 1024 uniform blocks (paired 64-row q-tiles,
    //    2x2 key/query-split waves, in-reg P), 4 blocks/CU co-resident
    flash_attn<<<dim3(1024), 256, 0, stream>>>(QKV, Vt, Ab);

    // 5) output projection -> fp32, XCD-swizzled 1D grid
    gemm_bt<float><<<dim3((EMB / 128) * (M / 128)), 256, 0, stream>>>(
        Ab, Woc, out, M, EMB, EMB, 1.0f, 0);
}

// Round 9
// 233.269 us; speedup vs baseline: 1.4791x; 1.0196x over previous
//
#include <hip/hip_runtime.h>
#include <hip/hip_bf16.h>

typedef __hip_bfloat16 bf16;
typedef __attribute__((ext_vector_type(8))) short short8;   // 8 bf16 (4 VGPRs)
typedef __attribute__((ext_vector_type(4))) short short4v;  // 4 bf16 (2 VGPRs)
typedef __attribute__((ext_vector_type(4))) float f32x4;
typedef unsigned int uint32;

#define MFMA16(a, b, c) __builtin_amdgcn_mfma_f32_16x16x32_bf16(a, b, c, 0, 0, 0)

// 16x16x16 bf16 MFMA (K=16): B-frag k-layout = quad*4+i, which exactly matches
// the C-layout rows (quad*4+r) of a prior 16x16 MFMA -> P can stay in regs.
__device__ __forceinline__ f32x4 MFMA16K16(short4v a, short4v b, f32x4 c) {
#if __has_builtin(__builtin_amdgcn_mfma_f32_16x16x16bf16_1k)
    return __builtin_amdgcn_mfma_f32_16x16x16bf16_1k(a, b, c, 0, 0, 0);
#else
    asm("v_mfma_f32_16x16x16_bf16 %0, %1, %2, %0" : "+v"(c) : "v"(a), "v"(b));
    return c;
#endif
}

constexpr int EMB   = 1024;
constexpr int SEQ   = 2048;
constexpr int BATCH = 4;
constexpr int NH    = 16;
constexpr int HD    = 64;
constexpr int QKVW  = 3 * EMB;   // 3072, stride of fused QKV buffer
// softmax scale 1/sqrt(64) folded into Q projection, in log2 units
constexpr float QSCALE = 0.125f * 1.44269504f;

// async global->LDS, 16B per lane; LDS dest = wave-uniform base + lane*16
__device__ __forceinline__ void gl_lds16(const bf16* g, bf16* l) {
    __builtin_amdgcn_global_load_lds(
        (const __attribute__((address_space(1))) void*)g,
        (__attribute__((address_space(3))) void*)l,
        16, 0, 0);
}

__device__ __forceinline__ float fexp2(float x) {
#if __has_builtin(__builtin_amdgcn_exp2f)
    return __builtin_amdgcn_exp2f(x);   // single v_exp_f32
#else
    return exp2f(x);
#endif
}

// pack two f32 -> bf16x2 (round-half-up): add 0x8000, take high halves via perm.
__device__ __forceinline__ uint32 pack2(float a, float b) {
    uint32 ua = __builtin_bit_cast(uint32, a) + 0x8000u;
    uint32 ub = __builtin_bit_cast(uint32, b) + 0x8000u;
    return __builtin_amdgcn_perm(ub, ua, 0x07060302u);  // {ub.hi16, ua.hi16}
}

__device__ __forceinline__ bf16 fbf16(float f) {        // fast scalar convert
    unsigned short u =
        (unsigned short)((__builtin_bit_cast(uint32, f) + 0x8000u) >> 16);
    return __builtin_bit_cast(bf16, u);
}

// ---------------------------------------------------------------------------
// One fused conversion kernel: x -> xc, {Wq,Wk,Wv} -> Wqkv (row-concat),
// Wo -> Woc. 3072 blocks: [0,2048) x, then 4x256 for the weights.
// ---------------------------------------------------------------------------
__global__ void convert_all(const float* __restrict__ x,
                            const float* __restrict__ wq,
                            const float* __restrict__ wk,
                            const float* __restrict__ wv,
                            const float* __restrict__ wo,
                            bf16* __restrict__ xc,
                            bf16* __restrict__ wqkv,
                            bf16* __restrict__ woc) {
    const int NX = BATCH * SEQ * EMB;
    const int NW = EMB * EMB;
    const float* src; bf16* dst; int n4, b0, nb;
    const int blk = blockIdx.x;
    if (blk < 2048)      { src = x;  dst = xc;          n4 = NX / 4; b0 = 0;    nb = 2048; }
    else if (blk < 2304) { src = wq; dst = wqkv;        n4 = NW / 4; b0 = 2048; nb = 256; }
    else if (blk < 2560) { src = wk; dst = wqkv + NW;   n4 = NW / 4; b0 = 2304; nb = 256; }
    else if (blk < 2816) { src = wv; dst = wqkv + 2*NW; n4 = NW / 4; b0 = 2560; nb = 256; }
    else                 { src = wo; dst = woc;         n4 = NW / 4; b0 = 2816; nb = 256; }
    for (int i = (blk - b0) * 256 + threadIdx.x; i < n4; i += nb * 256) {
        float4 v = ((const float4*)src)[i];
        uint2 o;
        o.x = pack2(v.x, v.y);
        o.y = pack2(v.z, v.w);
        ((uint2*)dst)[i] = o;
    }
}

// ---------------------------------------------------------------------------
// GEMM: C[M,N] = A[M,K]*B[N,K]^T (R4: dbuf + counted vmcnt, m-fastest XCD
// chunks -> per-XCD window = A 2MB + B 2MB = L2).
//
// R8 (VSPLIT): for the QKV GEMM, V-column tiles (n0 >= 2048) store directly
// to Vt[bh][d][s] transposed, eliminating the separate transpose_v kernel
// (its launch gap + 25 MB traffic) and the dead V-write to QKV. Per (i,j)
// fragment the 4 acc rows are 4 consecutive s at fixed (h,d) -> one 8B
// packed store. Tile/batch boundaries align (2048 % 128 == 0), and pack2
// rounding == fbf16 rounding, so output bits are identical to R7's path.
// ---------------------------------------------------------------------------
template <typename OutT, bool VSPLIT>
__global__ __launch_bounds__(256) void gemm_bt(const bf16* __restrict__ A,
                                               const bf16* __restrict__ B,
                                               OutT* __restrict__ C,
                                               bf16* __restrict__ Vt,
                                               int M, int N, int K,
                                               float oscale, int qlim) {
    __shared__ __align__(16) bf16 As[2][128 * 64];
    __shared__ __align__(16) bf16 Bs[2][128 * 64];

    const int t    = threadIdx.x;
    const int lane = t & 63;
    const int wid  = t >> 6;
    const int l16  = lane & 15;
    const int quad = lane >> 4;
    const int e    = l16 & 7;            // swizzle key for reads
    const int wm   = (wid >> 1) * 64;
    const int wn   = (wid & 1) * 64;

    const int nwg   = (int)gridDim.x;
    const int cpx   = nwg >> 3;                     // blocks per XCD chunk
    const int gx    = N >> 7;                       // tiles along N
    const int mrows = cpx / gx;                     // M-tile rows per chunk
    const int xcd   = (int)blockIdx.x & 7;
    const int local = (int)blockIdx.x >> 3;         // 0..cpx-1
    const int m0    = (xcd * mrows + (local % mrows)) * 128;
    const int n0    = (local / mrows) * 128;
    const float sc  = (n0 < qlim) ? oscale : 1.0f;

    f32x4 acc[4][4] = {};
    const int srow = lane >> 3;                    // 0..7
    const int scol = ((lane & 7) ^ srow) * 8;      // swizzled staging column

    auto stage = [&](int kt, int buf) {
        const int k0 = kt * 64;
        #pragma unroll
        for (int it = 0; it < 4; ++it) {
            int rb = it * 32 + wid * 8;  // wave-uniform LDS row base
            gl_lds16(&A[(size_t)(m0 + rb + srow) * K + k0 + scol], &As[buf][rb * 64]);
            gl_lds16(&B[(size_t)(n0 + rb + srow) * K + k0 + scol], &Bs[buf][rb * 64]);
        }
    };

    const int nk = K >> 6;                         // 16 for K=1024
    stage(0, 0);
    stage(1, 1);

    for (int kt = 0; kt < nk; ++kt) {
        const int cur = kt & 1;
        if (kt < nk - 1) __builtin_amdgcn_s_waitcnt(0x0F78);   // vmcnt(8)
        else             __builtin_amdgcn_s_waitcnt(0x0F70);   // vmcnt(0)
        __builtin_amdgcn_s_barrier();

        #pragma unroll
        for (int ks = 0; ks < 64; ks += 32) {
            const int cb = (ks >> 3) + quad;       // col-block before swizzle
            short8 af[4], bfr[4];
            #pragma unroll
            for (int i = 0; i < 4; ++i)
                af[i] = *(const short8*)&As[cur][(wm + i * 16 + l16) * 64 + ((cb ^ e) * 8)];
            #pragma unroll
            for (int j = 0; j < 4; ++j)
                bfr[j] = *(const short8*)&Bs[cur][(wn + j * 16 + l16) * 64 + ((cb ^ e) * 8)];
            #pragma unroll
            for (int i = 0; i < 4; ++i)
                #pragma unroll
                for (int j = 0; j < 4; ++j)
                    acc[i][j] = MFMA16(af[i], bfr[j], acc[i][j]);
        }

        __builtin_amdgcn_s_barrier();              // all waves done with buf[cur]
        if (kt + 2 < nk) stage(kt + 2, cur);       // prefetch into freed buffer
    }

    // C/D layout: col(n)=l16, row(m)=quad*4+reg  [m89/m91]
    if constexpr (VSPLIT) {
        if (n0 >= 2 * EMB) {
            // V tile: store transposed to Vt[(b*16+h)*64+d][s], 8B packed
            const int bq    = m0 >> 11;            // batch (tile-uniform)
            const int sbase = (m0 & 2047) + wm + quad * 4;
            bf16* vb = Vt + (size_t)bq * NH * HD * SEQ;
            #pragma unroll
            for (int j = 0; j < 4; ++j) {
                const int col = n0 + wn + j * 16 + l16 - 2 * EMB;  // 0..1023
                bf16* vrow = vb + (size_t)col * SEQ;   // col = h*64+d contiguous
                #pragma unroll
                for (int i = 0; i < 4; ++i) {
                    uint2 u;
                    u.x = pack2(acc[i][j][0], acc[i][j][1]);
                    u.y = pack2(acc[i][j][2], acc[i][j][3]);
                    *(uint2*)&vrow[sbase + i * 16] = u;
                }
            }
            return;
        }
    }
    #pragma unroll
    for (int i = 0; i < 4; ++i)
        #pragma unroll
        for (int j = 0; j < 4; ++j)
            #pragma unroll
            for (int r = 0; r < 4; ++r) {
                int row = m0 + wm + i * 16 + quad * 4 + r;
                int col = n0 + wn + j * 16 + l16;
                float v = acc[i][j][r] * sc;
                if constexpr (sizeof(OutT) == 2)
                    C[(size_t)row * N + col] = fbf16(v);
                else
                    C[(size_t)row * N + col] = (OutT)v;
            }
}

// ---------------------------------------------------------------------------
// Flash attention (causal), R7: 2x2 hybrid split (keys x queries) + in-reg P.
// Wave w = (kh=w>>1, qh=w&1) owns 32 keys x 32 queries, all 64 d; P stays in
// registers (S^T rows quad*4+r == K16 B-frag k-layout). Epilogue: partner
// exchange (w <-> w^2) + l-reduce, 2x/block. 1024 uniform blocks = 64 bh x
// 16 pairs {31-pr, pr}; LDS 33792 B -> 4 blocks/CU. Staging dbuf + vmcnt(4)
// + raw barriers (verified R1-R7). XCD chunk = 128 blocks = 8 bh -> 4 MB L2.
// ---------------------------------------------------------------------------
__global__ __launch_bounds__(256, 4) void flash_attn(const bf16* __restrict__ QKV,
                                                     const bf16* __restrict__ Vt,
                                                     bf16* __restrict__ O) {
    // 8448 floats = 33792 B.
    //   k-loop:   Ks [2][64*64] bf16 = floats [0..4096)
    //             VTs[2][64*64] bf16 = floats [4096..8192)
    //   epilogue (overlaying dead staging, separated by syncthreads):
    //             slots: 8 x [16][33] f32, slot(qh,dg)=(qh*4+dg)*528, [0..4224)
    //             Of   : 4 x [32][33] f32, Of(w)=w*1056, [0..4224)
    //             lred : [4 waves][64 q] f32 at [8192..8448)
    __shared__ __align__(16) float smemF[8448];
    bf16* Ks  = (bf16*)smemF;                 // [2][64*64] keys x d, swizzled
    bf16* VTs = (bf16*)smemF + 8192;          // [2][64*64] d x keys, swizzled
    constexpr int LRED = 8192;

    const int t    = threadIdx.x;
    const int lane = t & 63;
    const int w    = t >> 6;
    const int l16  = lane & 15;
    const int quad = lane >> 4;
    const int e    = l16 & 7;
    const int kh   = w >> 1;                         // key half 0/1
    const int qh   = w & 1;                          // query half 0/1

    // XCD-chunk swizzle: 1024 blocks, chunk 128 = 8 bh x 16 pr
    const int lin = (int)blockIdx.x;
    const int wg  = ((lin & 7) << 7) + (lin >> 3);
    const int bh  = wg >> 4;                         // 0..63
    const int pr  = wg & 15;                         // 0..15
    const int b   = bh >> 4, h = bh & 15;

    const bf16* Qp = QKV + (size_t)b * SEQ * QKVW + h * HD;
    const bf16* Kp = QKV + (size_t)b * SEQ * QKVW + EMB + h * HD;
    const bf16* Vp = Vt + (size_t)bh * HD * SEQ;
    bf16* Op = O + (size_t)b * SEQ * EMB + h * HD;

    const int srow = lane >> 3;
    const int scol = ((lane & 7) ^ srow) * 8;   // swizzled staging column

    auto stage = [&](int kt, int buf) {
        const int kbase = kt * 64;
        #pragma unroll
        for (int it = 0; it < 2; ++it) {
            int rb = it * 32 + w * 8;
            gl_lds16(&Kp[(size_t)(kbase + rb + srow) * QKVW + scol], &Ks[buf * 4096 + rb * 64]);
            gl_lds16(&Vp[(size_t)(rb + srow) * SEQ + kbase + scol], &VTs[buf * 4096 + rb * 64]);
        }
    };

    for (int pass = 0; pass < 2; ++pass) {
        const int qt = pass ? pr : 31 - pr;          // heavy q-tile first
        const int q0 = qt * 64;

        // Q fragments (B-operand, this wave's 32 queries): B[k=quad*8+i][n=l16]
        short8 bQ[2][2];
        #pragma unroll
        for (int qg = 0; qg < 2; ++qg) {
            const size_t qr = (size_t)(q0 + qh * 32 + qg * 16 + l16) * QKVW;
            bQ[qg][0] = *(const short8*)&Qp[qr + quad * 8];
            bQ[qg][1] = *(const short8*)&Qp[qr + 32 + quad * 8];
        }

        f32x4 o[4][2] = {};          // partial O^T[dg][qg] over wave's 32 keys
        float lrow[2] = {0.f, 0.f};

        const int ntiles = qt + 1;

        stage(0, 0);
        if (ntiles > 1) stage(1, 1);

        for (int kt = 0; kt < ntiles; ++kt) {
            const int cur = kt & 1;
            const int kbase = kt * 64;
            if (kt < ntiles - 1) __builtin_amdgcn_s_waitcnt(0x0F74);   // vmcnt(4)
            else                 __builtin_amdgcn_s_waitcnt(0x0F70);   // vmcnt(0)
            __builtin_amdgcn_s_barrier();

            const bool diag = (kt == ntiles - 1);
            if (!(diag && kh == 1 && qh == 0)) {     // skip fully-masked wave
                // --- K fragments: wave's 32 keys (2 groups), d 0..63 ---
                const bf16* Kb = &Ks[cur * 4096];
                short8 kf[2][2];
                #pragma unroll
                for (int kg = 0; kg < 2; ++kg) {
                    const int krow = (kh * 32 + kg * 16 + l16) * 64;
                    kf[kg][0] = *(const short8*)&Kb[krow + ((quad ^ e) * 8)];
                    kf[kg][1] = *(const short8*)&Kb[krow + (((4 + quad) ^ e) * 8)];
                }

                // --- S^T = K Q^T; exp; pack to in-reg P fragments ---
                short4v pb[2][2];
                const bool needmask = diag && (kh == qh);
                #pragma unroll
                for (int kg = 0; kg < 2; ++kg) {
                    const int kgb = kbase + kh * 32 + kg * 16 + quad * 4;
                    #pragma unroll
                    for (int qg = 0; qg < 2; ++qg) {
                        f32x4 acc = {};
                        acc = MFMA16(kf[kg][0], bQ[qg][0], acc);
                        acc = MFMA16(kf[kg][1], bQ[qg][1], acc);
                        // col=q=l16 (+qh*32+qg*16), row=key=quad*4+r
                        float p0 = fexp2(acc[0]);
                        float p1 = fexp2(acc[1]);
                        float p2 = fexp2(acc[2]);
                        float p3 = fexp2(acc[3]);
                        if (needmask) {
                            const int qglob = q0 + qh * 32 + qg * 16 + l16;
                            if (kgb     > qglob) p0 = 0.f;
                            if (kgb + 1 > qglob) p1 = 0.f;
                            if (kgb + 2 > qglob) p2 = 0.f;
                            if (kgb + 3 > qglob) p3 = 0.f;
                        }
                        lrow[qg] += (p0 + p1) + (p2 + p3);
                        uint2 u;
                        u.x = pack2(p0, p1);
                        u.y = pack2(p2, p3);
                        pb[kg][qg] = __builtin_bit_cast(short4v, u);
                    }
                }

                // --- O^T += V^T P^T : A=V^T[16d][16k] b64, B=pb in regs ---
                const bf16* Vb = &VTs[cur * 4096];
                #pragma unroll
                for (int dg = 0; dg < 4; ++dg) {
                    #pragma unroll
                    for (int kg = 0; kg < 2; ++kg) {
                        const short4v vf = *(const short4v*)&Vb[(dg * 16 + l16) * 64 +
                            (((4 * kh + 2 * kg + (quad >> 1)) ^ e) * 8) + (quad & 1) * 4];
                        #pragma unroll
                        for (int qg = 0; qg < 2; ++qg)
                            o[dg][qg] = MFMA16K16(vf, pb[kg][qg], o[dg][qg]);
                    }
                }
            }

            __builtin_amdgcn_s_barrier();
            if (kt + 2 < ntiles) stage(kt + 2, cur);
        }

        // ---- epilogue: partner exchange (w <-> w^2), rescale, store ----
        #pragma unroll
        for (int qg = 0; qg < 2; ++qg) {            // reduce l over quads
            float l = lrow[qg];
            l += __shfl_xor(l, 16);
            l += __shfl_xor(l, 32);
            lrow[qg] = l;
        }
        if (quad == 0) {
            #pragma unroll
            for (int qg = 0; qg < 2; ++qg)
                smemF[LRED + w * 64 + qg * 16 + l16] = lrow[qg];
        }
        // step A: write partials for the d-half the partner finalizes
        #pragma unroll
        for (int dg = 0; dg < 4; ++dg) {
            if ((dg >> 1) != kh) {
                float* s = smemF + (qh * 4 + dg) * 528;
                #pragma unroll
                for (int r = 0; r < 4; ++r)
                    #pragma unroll
                    for (int qg = 0; qg < 2; ++qg)
                        s[(quad * 4 + r) * 33 + qg * 16 + l16] = o[dg][qg][r];
            }
        }
        __syncthreads();
        // step B: add partner partials for own finalized d-half; compute 1/l
        float rlq[2];
        {
            #pragma unroll
            for (int dg = 0; dg < 4; ++dg) {
                if ((dg >> 1) == kh) {
                    const float* s = smemF + (qh * 4 + dg) * 528;
                    #pragma unroll
                    for (int r = 0; r < 4; ++r)
                        #pragma unroll
                        for (int qg = 0; qg < 2; ++qg)
                            o[dg][qg][r] += s[(quad * 4 + r) * 33 + qg * 16 + l16];
                }
            }
            #pragma unroll
            for (int qg = 0; qg < 2; ++qg)
                rlq[qg] = 1.0f / (lrow[qg] +
                                  smemF[LRED + (w ^ 2) * 64 + qg * 16 + l16]);
        }
        __syncthreads();   // slots free before Of overwrite (same region)
        // step C: write finalized 32d x 32q to wave-private Of for transpose
        {
            float* Of = smemF + w * 1056;           // [32 d][33 q]
            #pragma unroll
            for (int dg = 0; dg < 4; ++dg) {
                if ((dg >> 1) == kh) {
                    const int dl = (dg & 1) * 16;
                    #pragma unroll
                    for (int r = 0; r < 4; ++r)
                        #pragma unroll
                        for (int qg = 0; qg < 2; ++qg)
                            Of[(dl + quad * 4 + r) * 33 + qg * 16 + l16] =
                                o[dg][qg][r] * rlq[qg];
                }
            }
            // step D: transposed readback (wave-private, lgkm-ordered), store
            const int qloc = lane >> 1, half = lane & 1;
            float f[16];
            #pragma unroll
            for (int j = 0; j < 16; ++j) f[j] = Of[(half * 16 + j) * 33 + qloc];
            uint4 ua, ub;
            ua.x = pack2(f[0],  f[1]);  ua.y = pack2(f[2],  f[3]);
            ua.z = pack2(f[4],  f[5]);  ua.w = pack2(f[6],  f[7]);
            ub.x = pack2(f[8],  f[9]);  ub.y = pack2(f[10], f[11]);
            ub.z = pack2(f[12], f[13]); ub.w = pack2(f[14], f[15]);
            bf16* orow = Op + (size_t)(q0 + qh * 32 + qloc) * EMB + kh * 32 + half * 16;
            *(uint4*)&orow[0] = ua;
            *(uint4*)&orow[8] = ub;
        }
        __syncthreads();   // scratch free before next pass's stage() overwrites
    }
}

// ---------------------------------------------------------------------------
extern "C" void kernel_launch(void* const* d_in, const int* in_sizes, int n_in,
                              void* d_out, int out_size, void* d_ws, size_t ws_size,
                              hipStream_t stream) {
    const float* x  = (const float*)d_in[0];
    const float* Wq = (const float*)d_in[1];
    const float* Wk = (const float*)d_in[2];
    const float* Wv = (const float*)d_in[3];
    const float* Wo = (const float*)d_in[4];
    float* out = (float*)d_out;            // reference output dtype: float32
    bf16*  ws  = (bf16*)d_ws;

    const int M  = BATCH * SEQ;            // 8192
    const int NX = M * EMB;                // 8388608
    const int NW = EMB * EMB;              // 1048576

    // workspace (bf16 elems), total 92,274,688 B
    bf16* xc   = ws;                       // [8192][1024]; dead after QKV GEMM
    bf16* Ab   = xc;                       // attention out aliases xc
    bf16* Wqkv = ws + (size_t)NX;          // [3072][1024] fused weights
    bf16* Woc  = Wqkv + 3 * (size_t)NW;
    bf16* QKV  = Woc + NW;                 // [8192][3072] (V cols unused now)
    bf16* Vt   = QKV + (size_t)M * QKVW;   // [64 bh][64 d][2048 s]

    // 1) one fused conversion launch
    convert_all<<<3072, 256, 0, stream>>>(x, Wq, Wk, Wv, Wo, xc, Wqkv, Woc);

    // 2) fused QKV projection (Q cols pre-scaled by QSCALE); V-column tiles
    //    store straight to Vt transposed (replaces transpose_v kernel)
    gemm_bt<bf16, true><<<dim3((QKVW / 128) * (M / 128)), 256, 0, stream>>>(
        xc, Wqkv, QKV, Vt, M, QKVW, EMB, QSCALE, EMB);

    // 3) causal flash attention: 1024 uniform blocks (paired 64-row q-tiles,
    //    2x2 key/query-split waves, in-reg P), 4 blocks/CU co-resident
    flash_attn<<<dim3(1024), 256, 0, stream>>>(QKV, Vt, Ab);

    // 4) output projection -> fp32, XCD-swizzled 1D grid
    gemm_bt<float, false><<<dim3((EMB / 128) * (M / 128)), 256, 0, stream>>>(
        Ab, Woc, out, nullptr, M, EMB, EMB, 1.0f, 0);
}